// Round 10
// baseline (294.125 us; speedup 1.0000x reference)
//
#include <hip/hip_runtime.h>
#include <hip/hip_bf16.h>

#define DM 1024
#define BS 4
#define SS 1024
#define NH 16

typedef __attribute__((ext_vector_type(8))) short bf16x8;
typedef __attribute__((ext_vector_type(4))) float f32x4;

__device__ inline unsigned short f2bf(float x) {
    union { float f; unsigned u; } v; v.f = x;
    unsigned r = v.u + 0x7fffu + ((v.u >> 16) & 1u);
    return (unsigned short)(r >> 16);
}
__device__ inline float bf2f(unsigned short u) {
    union { unsigned u; float f; } v; v.u = ((unsigned)u) << 16;
    return v.f;
}

template<typename T> __device__ inline void store1(T* p, float v);
template<> __device__ inline void store1<float>(float* p, float v) { *p = v; }
template<> __device__ inline void store1<unsigned short>(unsigned short* p, float v) { *p = f2bf(v); }

// async global->LDS, 16B per lane; LDS dest = wave-uniform base + lane*16
__device__ inline void glds16(const unsigned short* g, unsigned short* l) {
    __builtin_amdgcn_global_load_lds(
        (const __attribute__((address_space(1))) unsigned int*)g,
        (__attribute__((address_space(3))) unsigned int*)l, 16, 0, 0);
}

// fp32 -> bf16 elementwise, float4/ushort4 vectorized, grid-stride
__global__ __launch_bounds__(256) void cvt_bf16(const float* __restrict__ in,
                                                unsigned short* __restrict__ out, int n4)
{
    int i = blockIdx.x * blockDim.x + threadIdx.x;
    const int stride = gridDim.x * blockDim.x;
    for (; i < n4; i += stride) {
        float4 v = reinterpret_cast<const float4*>(in)[i];
        ushort4 o;
        o.x = f2bf(v.x); o.y = f2bf(v.y); o.z = f2bf(v.z); o.w = f2bf(v.w);
        reinterpret_cast<ushort4*>(out)[i] = o;
    }
}

// Batched C = scale*(A @ B^T) + bias. All-bf16 inputs, glds16 staging, 2-phase dbuf
// (round-8/9 verified structure). BM=128 BN=64 BK=32, 4 waves (2x2 of 64x32).
// Grid: (N/64, M/128, Z); z -> (zb=z/H, zh=z%H) offsets.
template<typename TO>
__global__ __launch_bounds__(256) void gemmb_bt(
    const unsigned short* __restrict__ A, int lda, long long sAb, long long sAh,
    const unsigned short* __restrict__ B, int ldb, long long sBb, long long sBh,
    TO* __restrict__ C, int ldc, long long sCb, long long sCh,
    const float* __restrict__ bias, int K, int H, float scale)
{
    __shared__ unsigned short lA[2][128 * 32];   // 8KB x2
    __shared__ unsigned short lB[2][64 * 32];    // 4KB x2

    const int tid = threadIdx.x;
    const int wid = tid >> 6, lane = tid & 63;
    const int wr = wid >> 1, wc = wid & 1;
    const int r0 = lane & 15;
    const int kq = (lane >> 4) * 8;
    const int srow = lane >> 2;          // 16 rows per wave-glds16
    const int scol = (lane & 3) * 8;     // 4 lanes x 16B = 64B row

    const int z = blockIdx.z, zb = z / H, zh = z % H;
    const unsigned short* Ap = A + sAb * zb + sAh * zh
        + ((long long)blockIdx.y * 128 + srow) * lda + scol;
    const unsigned short* Bp = B + sBb * zb + sBh * zh
        + ((long long)blockIdx.x * 64 + srow) * ldb + scol;
    TO* Cp = C + sCb * zb + sCh * zh
        + (long long)blockIdx.y * 128 * ldc + blockIdx.x * 64;

    f32x4 acc[4][2];
    #pragma unroll
    for (int m = 0; m < 4; ++m)
        #pragma unroll
        for (int n = 0; n < 2; ++n)
            acc[m][n] = f32x4{0.f, 0.f, 0.f, 0.f};

    // prologue: stage tile 0 (wave wid: A rows [wid*32,+32), B rows [wid*16,+16))
    glds16(Ap + (long long)(wid * 32) * lda, &lA[0][wid * 1024]);
    glds16(Ap + (long long)(wid * 32 + 16) * lda, &lA[0][wid * 1024 + 512]);
    glds16(Bp + (long long)(wid * 16) * ldb, &lB[0][wid * 512]);
    __syncthreads();

    const int NT = K / 32;
    int cur = 0;
    for (int t = 0; t < NT; ++t) {
        if (t + 1 < NT) {
            glds16(Ap + (long long)(wid * 32) * lda + (t + 1) * 32, &lA[cur ^ 1][wid * 1024]);
            glds16(Ap + (long long)(wid * 32 + 16) * lda + (t + 1) * 32, &lA[cur ^ 1][wid * 1024 + 512]);
            glds16(Bp + (long long)(wid * 16) * ldb + (t + 1) * 32, &lB[cur ^ 1][wid * 512]);
        }
        bf16x8 af[4], bfr[2];
        #pragma unroll
        for (int m = 0; m < 4; ++m)
            af[m] = *reinterpret_cast<const bf16x8*>(&lA[cur][(wr * 64 + m * 16 + r0) * 32 + kq]);
        #pragma unroll
        for (int n = 0; n < 2; ++n)
            bfr[n] = *reinterpret_cast<const bf16x8*>(&lB[cur][(wc * 32 + n * 16 + r0) * 32 + kq]);
        #pragma unroll
        for (int m = 0; m < 4; ++m)
            #pragma unroll
            for (int n = 0; n < 2; ++n)
                acc[m][n] = __builtin_amdgcn_mfma_f32_16x16x32_bf16(af[m], bfr[n], acc[m][n], 0, 0, 0);
        __syncthreads();
        cur ^= 1;
    }

    const int cf = lane & 15, rf = (lane >> 4) * 4;
    #pragma unroll
    for (int m = 0; m < 4; ++m) {
        #pragma unroll
        for (int n = 0; n < 2; ++n) {
            int col = wc * 32 + n * 16 + cf;
            float bv = bias ? bias[blockIdx.x * 64 + col] : 0.0f;
            #pragma unroll
            for (int j = 0; j < 4; ++j) {
                int row = wr * 64 + m * 16 + rf + j;
                store1<TO>(&Cp[(long long)row * ldc + col], acc[m][n][j] * scale + bv);
            }
        }
    }
}

// vT[(b*NH+h)*64 + d][t] = v_p[b][t][h*64+d]   (round-1 verified)
__global__ __launch_bounds__(256) void transpose_vh(const unsigned short* __restrict__ vp,
                                                    unsigned short* __restrict__ vT)
{
    __shared__ unsigned short tile[64][65];
    const int bh = blockIdx.y;
    const int b = bh >> 4, h = bh & 15;
    const long long t0 = (long long)blockIdx.x * 64;
    const int tid = threadIdx.x;
    #pragma unroll
    for (int kk = 0; kk < 4; ++kk) {
        int l = tid + kk * 256;
        int row = l >> 4, c4 = l & 15;
        const unsigned short* src = vp + ((long long)b * SS + t0 + row) * DM + h * 64 + c4 * 4;
        ushort4 val = *reinterpret_cast<const ushort4*>(src);
        tile[row][c4 * 4 + 0] = val.x;
        tile[row][c4 * 4 + 1] = val.y;
        tile[row][c4 * 4 + 2] = val.z;
        tile[row][c4 * 4 + 3] = val.w;
    }
    __syncthreads();
    #pragma unroll
    for (int kk = 0; kk < 4; ++kk) {
        int l = tid + kk * 256;
        int d = l >> 4, i4 = l & 15;
        ushort4 o;
        o.x = tile[i4 * 4 + 0][d];
        o.y = tile[i4 * 4 + 1][d];
        o.z = tile[i4 * 4 + 2][d];
        o.w = tile[i4 * 4 + 3][d];
        *reinterpret_cast<ushort4*>(vT + ((long long)bh * 64 + d) * SS + t0 + i4 * 4) = o;
    }
}

// In-place row softmax over the attnw region:
//   input:  bf16 S row (1024 elems = 2KB) at the START of each 4KB attnw row slot
//   output: f32 softmax row (1024 elems = 4KB) overwriting the slot
// One wave per row; lane holds 16 elems in regs (read fully before overwrite ->
// self-clobber safe, no cross-block hazard). Grid: totalRows/4 blocks, 256 thr.
__global__ __launch_bounds__(256) void softmax_inplace(float* __restrict__ attnw)
{
    const int w = threadIdx.x >> 6, lane = threadIdx.x & 63;
    const long long row = (long long)blockIdx.x * 4 + w;
    float* rowp = attnw + row * 1024;

    // load 32B of bf16 S (16 elems) per lane
    uint4 u0 = reinterpret_cast<const uint4*>(rowp)[lane * 2];
    uint4 u1 = reinterpret_cast<const uint4*>(rowp)[lane * 2 + 1];
    unsigned a[8] = {u0.x, u0.y, u0.z, u0.w, u1.x, u1.y, u1.z, u1.w};
    float v[16];
    #pragma unroll
    for (int i = 0; i < 8; ++i) {
        v[2 * i]     = bf2f((unsigned short)(a[i] & 0xffffu));
        v[2 * i + 1] = bf2f((unsigned short)(a[i] >> 16));
    }

    float m = v[0];
    #pragma unroll
    for (int i = 1; i < 16; ++i) m = fmaxf(m, v[i]);
    #pragma unroll
    for (int o = 1; o < 64; o <<= 1) m = fmaxf(m, __shfl_xor(m, o));

    float e[16];
    float s = 0.f;
    #pragma unroll
    for (int i = 0; i < 16; ++i) { e[i] = __expf(v[i] - m); s += e[i]; }
    #pragma unroll
    for (int o = 1; o < 64; o <<= 1) s += __shfl_xor(s, o);
    const float inv = 1.0f / s;

    float4* dst = reinterpret_cast<float4*>(rowp) + lane * 4;
    #pragma unroll
    for (int k = 0; k < 4; ++k) {
        float4 o4;
        o4.x = e[4 * k + 0] * inv;
        o4.y = e[4 * k + 1] * inv;
        o4.z = e[4 * k + 2] * inv;
        o4.w = e[4 * k + 3] * inv;
        dst[k] = o4;
    }
}

extern "C" void kernel_launch(void* const* d_in, const int* in_sizes, int n_in,
                              void* d_out, int out_size, void* d_ws, size_t ws_size,
                              hipStream_t stream) {
    (void)in_sizes; (void)n_in; (void)out_size; (void)ws_size;
    const float* v    = (const float*)d_in[0];
    const float* q    = (const float*)d_in[2];
    const float* wq_w = (const float*)d_in[3];
    const float* wq_b = (const float*)d_in[4];
    const float* wv_w = (const float*)d_in[5];
    const float* wv_b = (const float*)d_in[6];
    const float* dw   = (const float*)d_in[7];
    const float* db   = (const float*)d_in[8];

    // workspace: 5 x 4M bf16 = 40 MB
    unsigned short* q_p = (unsigned short*)d_ws;
    unsigned short* v_p = q_p + (4 << 20);
    unsigned short* k_p = v_p + (4 << 20);
    unsigned short* vT  = k_p + (4 << 20);
    unsigned short* cc  = vT  + (4 << 20);

    float* out0   = (float*)d_out;
    float* attnw  = out0 + (long long)BS * SS * DM;

    // bf16 S buffer lives INSIDE the attnw region: S row r (2KB bf16) at the
    // start of attnw row slot r (4KB). ldc_S = 2048 bf16 elems = 4KB stride.
    unsigned short* Sb = (unsigned short*)attnw;

    // cvt buffers parked in attnw region (dead once K1 starts overwriting it)
    unsigned short* qb  = (unsigned short*)attnw;
    unsigned short* vb  = qb  + (4 << 20);
    unsigned short* wqb = vb  + (4 << 20);
    unsigned short* wvb = wqb + (1 << 20);
    // dwb reuses q_p's slot AFTER K1 (q_p dead by then)
    unsigned short* dwb = q_p;

    dim3 blk(256);
    dim3 projGrid(DM / 64, BS * SS / 128, 1);    // (16, 32, 1)

    cvt_bf16<<<dim3(1024), blk, 0, stream>>>(q, qb, (BS * SS * DM) / 4);
    cvt_bf16<<<dim3(1024), blk, 0, stream>>>(v, vb, (BS * SS * DM) / 4);
    cvt_bf16<<<dim3(256),  blk, 0, stream>>>(wq_w, wqb, (DM * DM) / 4);
    cvt_bf16<<<dim3(256),  blk, 0, stream>>>(wv_w, wvb, (DM * DM) / 4);

    // projections (H=1, no batching)
    gemmb_bt<unsigned short><<<projGrid, blk, 0, stream>>>(
        qb, DM, 0, 0, wqb, DM, 0, 0, q_p, DM, 0, 0, wq_b, DM, 1, 1.0f);
    gemmb_bt<unsigned short><<<projGrid, blk, 0, stream>>>(
        vb, DM, 0, 0, wvb, DM, 0, 0, v_p, DM, 0, 0, wv_b, DM, 1, 1.0f);
    gemmb_bt<unsigned short><<<projGrid, blk, 0, stream>>>(
        v_p, DM, 0, 0, wvb, DM, 0, 0, k_p, DM, 0, 0, wv_b, DM, 1, 1.0f);

    transpose_vh<<<dim3(16, 64), blk, 0, stream>>>(v_p, vT);

    // K1: S[z] = 0.125 * q_p[b,:,h*64:] @ k_p[b,:,h*64:]^T  -> bf16, ldc=2048
    gemmb_bt<unsigned short><<<dim3(16, 8, 64), blk, 0, stream>>>(
        q_p, DM, (long long)SS * DM, 64,
        k_p, DM, (long long)SS * DM, 64,
        Sb, 2048, (long long)NH * SS * 2048, (long long)SS * 2048,
        nullptr, 64, NH, 0.125f);

    // K3: cc[b,:,h*64:] = S[z] @ vT[z]^T   (raw logits @ V, bug preserved)
    gemmb_bt<unsigned short><<<dim3(1, 8, 64), blk, 0, stream>>>(
        Sb, 2048, (long long)NH * SS * 2048, (long long)SS * 2048,
        vT, SS, (long long)NH * 64 * SS, (long long)64 * SS,
        cc, DM, (long long)SS * DM, 64,
        nullptr, SS, NH, 1.0f);

    // dense output
    cvt_bf16<<<dim3(256), blk, 0, stream>>>(dw, dwb, (DM * DM) / 4);
    gemmb_bt<float><<<projGrid, blk, 0, stream>>>(
        cc, DM, 0, 0, dwb, DM, 0, 0, out0, DM, 0, 0, db, DM, 1, 1.0f);

    // K2: softmax in place over attnw region (reads bf16 S, writes f32 rows)
    softmax_inplace<<<dim3(BS * NH * SS / 4), blk, 0, stream>>>(attnw);
}